// Round 4
// baseline (164.228 us; speedup 1.0000x reference)
//
#include <hip/hip_runtime.h>
#include <math.h>

#ifndef M_PI
#define M_PI 3.14159265358979323846
#endif

#define T 2048
#define EDGE 256
#define TT 1536            // trimmed timesteps
#define PHA_N 50
#define AMP_N 30
#define NBANDS 80
#define NBINS 18
#define NBC 16             // B*C = 2*8
#define FMAX 768           // forward DFT bins stored [0, FMAX); max needed bin = 634
#define NCH 8              // t-chunks for forward DFT
#define CHLEN (T / NCH)    // 256

// Inclusive frequency-bin range [fl, fh] for a band, replicating the
// reference's float32 band edges vs exact quarter-Hz freq grid.
__device__ __forceinline__ void band_range(int band, int* fl, int* fh) {
    double lo, hi;
    if (band < PHA_N) {
        double mid = 2.0 + (double)band * (18.0 / 49.0);   // linspace(2,20,50)
        lo = (double)(float)(mid * 0.75);
        hi = (double)(float)(mid * 1.25);
    } else {
        int j = band - PHA_N;
        double mid = 60.0 + (double)j * (81.0 / 29.0);     // linspace(60,141,30)
        lo = (double)(float)(mid * 0.875);
        hi = (double)(float)(mid * 1.125);
    }
    int l = (int)ceil(lo * 4.0);     // freq = 0.25*f ; f >= 4*lo
    int h = (int)floor(hi * 4.0);    // f <= 4*hi
    if (l < 1) l = 1;
    if (h > FMAX - 1) h = FMAX - 1;
    *fl = l; *fh = h;
}

// Kernel A: chunked forward DFT partials via complex oscillator recurrence.
// Depth-2 float4 register prefetch hides LDS latency at low occupancy.
__global__ void dft_kernel(const float* __restrict__ x, double* __restrict__ Xp) {
    __shared__ float xs[CHLEN + 8];        // pad 8 floats (2 float4) of zeros
    const int bc = blockIdx.x;
    const int fb = blockIdx.y;
    const int ch = blockIdx.z;
    const int tid = threadIdx.x;
    const int t0 = ch * CHLEN;
    if (tid < CHLEN) xs[tid] = x[bc * T + t0 + tid];
    if (tid < 8) xs[CHLEN + tid] = 0.0f;
    __syncthreads();
    const int f = fb * 256 + tid;
    const double om = 2.0 * M_PI / (double)T;
    double s0, c0, sw, cw;
    sincos(om * (double)((f * t0) & (T - 1)), &s0, &c0);
    sincos(om * (double)(f & (T - 1)), &sw, &cw);
    double curR = c0, curI = -s0;          // e^{-i th0}
    const double wR = cw, wI = -sw;        // e^{-i om f}
    double accR = 0.0, accI = 0.0;
    const float4* xs4 = (const float4*)xs; // 64 data quads + 2 pad quads
    float4 a0 = xs4[0], a1 = xs4[1];
    for (int q = 0; q < CHLEN / 4; ++q) {
        float4 a2 = xs4[q + 2];            // prefetch, used 2 iters later
        #pragma unroll
        for (int u = 0; u < 4; ++u) {
            double v = (double)((u == 0) ? a0.x : (u == 1) ? a0.y : (u == 2) ? a0.z : a0.w);
            accR += v * curR;
            accI += v * curI;
            double nR = curR * wR - curI * wI;
            double nI = curR * wI + curI * wR;
            curR = nR; curI = nI;
        }
        a0 = a1; a1 = a2;
    }
    Xp[(size_t)((bc * FMAX + f) * NCH + ch) * 2 + 0] = accR;
    Xp[(size_t)((bc * FMAX + f) * NCH + ch) * 2 + 1] = accI;
}

// Kernel B: per (bc, band, t-half) analytic-signal synthesis via oscillator
// recurrence over band bins. 3 t-values/thread; depth-2 LDS prefetch.
#define NJ 3
__global__ void band_kernel(const double* __restrict__ Xp,
                            unsigned char* __restrict__ idx_buf,
                            float* __restrict__ amp_buf) {
    __shared__ double sXr[164];
    __shared__ double sXi[164];
    const int bc = blockIdx.x;
    const int band = blockIdx.y;
    const int half = blockIdx.z;
    const int tid = threadIdx.x;
    int fl, fh;
    band_range(band, &fl, &fh);
    const int nb = fh - fl + 1;
    for (int i = tid; i < nb; i += 256) {
        const double* p = Xp + (size_t)((bc * FMAX + fl + i) * NCH) * 2;
        double r = 0.0, im = 0.0;
        #pragma unroll
        for (int c = 0; c < NCH; ++c) { r += p[2 * c]; im += p[2 * c + 1]; }
        sXr[i] = r; sXi[i] = im;
    }
    if (tid < 2) { sXr[nb + tid] = 0.0; sXi[nb + tid] = 0.0; }  // prefetch pad
    __syncthreads();

    const double om = 2.0 * M_PI / (double)T;
    double curR[NJ], curI[NJ], wR[NJ], wI[NJ], accR[NJ], accI[NJ];
    #pragma unroll
    for (int j = 0; j < NJ; ++j) {
        const int t = tid + j * 256 + half * 768 + EDGE;
        double s, c;
        sincos(om * (double)((fl * t) & (T - 1)), &s, &c);
        curR[j] = c; curI[j] = s;          // e^{+i om fl t}
        sincos(om * (double)(t & (T - 1)), &s, &c);
        wR[j] = c; wI[j] = s;              // e^{+i om t}
        accR[j] = 0.0; accI[j] = 0.0;
    }
    double Xr0 = sXr[0], Xi0 = sXi[0];
    double Xr1 = sXr[1], Xi1 = sXi[1];
    for (int i = 0; i < nb; ++i) {
        double Xr2 = sXr[i + 2], Xi2 = sXi[i + 2];   // depth-2 prefetch
        #pragma unroll
        for (int j = 0; j < NJ; ++j) {
            accR[j] += Xr0 * curR[j] - Xi0 * curI[j];
            accI[j] += Xr0 * curI[j] + Xi0 * curR[j];
            double nR = curR[j] * wR[j] - curI[j] * wI[j];
            double nI = curR[j] * wI[j] + curI[j] * wR[j];
            curR[j] = nR; curI[j] = nI;
        }
        Xr0 = Xr1; Xi0 = Xi1; Xr1 = Xr2; Xi1 = Xi2;
    }
    #pragma unroll
    for (int j = 0; j < NJ; ++j) {
        const int trel = tid + j * 256 + half * 768;
        if (band < PHA_N) {
            double pha = atan2(accI[j], accR[j]);        // (-pi, pi]
            double width = 2.0 * M_PI / (double)NBINS;
            int b = (int)floor((pha + M_PI) / width);
            if (b < 0) b = 0;
            if (b > NBINS - 1) b = NBINS - 1;
            idx_buf[(size_t)(bc * PHA_N + band) * TT + trel] = (unsigned char)b;
        } else {
            double amp = sqrt(accR[j] * accR[j] + accI[j] * accI[j]) * (2.0 / (double)T);
            amp_buf[(size_t)(bc * AMP_N + (band - PHA_N)) * TT + trel] = (float)amp;
        }
    }
}

// Kernel C: per (bc, phase band p): fused counts + per-amp-band bin sums + MI.
#define PK 19   // padded bin stride for partials
#define NROW 31 // 30 amp bands + counts row
__global__ void mi_kernel(const unsigned char* __restrict__ idx_buf,
                          const float* __restrict__ amp_buf,
                          float* __restrict__ out) {
    __shared__ float part[NROW * 8 * PK];     // row = tid = a*8+g
    __shared__ float sums[NROW * NBINS];
    const int blk = blockIdx.x;               // bc*50 + p
    const int bc = blk / PHA_N;
    const int p = blk % PHA_N;
    const int tid = threadIdx.x;

    for (int i = tid; i < NROW * 8 * PK; i += 256) part[i] = 0.0f;
    __syncthreads();

    if (tid < NROW * 8) {
        const int a = tid >> 3;     // 0..30 (30 == counts)
        const int g = tid & 7;      // contiguous 192-t chunk per thread
        const unsigned int* sp =
            (const unsigned int*)(idx_buf + (size_t)(bc * PHA_N + p) * TT) + g * 48;
        const float4* ap = (a < AMP_N)
            ? (const float4*)(amp_buf + (size_t)(bc * AMP_N + a) * TT) + g * 48
            : (const float4*)0;
        float* myp = part + tid * PK;
        for (int it = 0; it < 48; ++it) {
            const unsigned int pk = sp[it];
            float4 v;
            if (a < AMP_N) v = ap[it];
            else { v.x = 1.0f; v.y = 1.0f; v.z = 1.0f; v.w = 1.0f; }
            myp[pk & 0xff]         += v.x;
            myp[(pk >> 8) & 0xff]  += v.y;
            myp[(pk >> 16) & 0xff] += v.z;
            myp[(pk >> 24) & 0xff] += v.w;
        }
    }
    __syncthreads();

    for (int i = tid; i < NROW * NBINS; i += 256) {
        const int a = i / NBINS, k = i - a * NBINS;
        float s = 0.0f;
        #pragma unroll
        for (int g = 0; g < 8; ++g) s += part[(a * 8 + g) * PK + k];
        sums[i] = s;
    }
    __syncthreads();

    if (tid < AMP_N) {
        const int a = tid;
        double m[NBINS], tot = 0.0;
        for (int k = 0; k < NBINS; ++k) {
            double cnt = (double)sums[AMP_N * NBINS + k];   // counts row
            double denom = cnt > 1e-9 ? cnt : 1e-9;
            m[k] = (double)sums[a * NBINS + k] / denom;
            tot += m[k];
        }
        double dt = tot > 1e-9 ? tot : 1e-9;
        double acc = 0.0;
        for (int k = 0; k < NBINS; ++k) {
            double pr = m[k] / dt;
            acc += pr * log(pr + 1e-9);
        }
        const double lognb = log((double)NBINS);
        double mi = (lognb + acc) / lognb;
        out[(size_t)(bc * PHA_N + p) * AMP_N + a] = (float)mi;
    }
}

extern "C" void kernel_launch(void* const* d_in, const int* in_sizes, int n_in,
                              void* d_out, int out_size, void* d_ws, size_t ws_size,
                              hipStream_t stream) {
    const float* x = (const float*)d_in[0];
    float* out = (float*)d_out;
    char* ws = (char*)d_ws;
    // workspace layout (all regions fully written before read each call):
    //   idx_buf: 16*50*1536 u8                    = 1,228,800 B
    //   amp_buf: 16*30*1536 f32                   = 2,949,120 B
    //   Xp:      16*768*8 chunks complex double   = 1,572,864 B   (~5.5 MB total)
    unsigned char* idx_buf = (unsigned char*)ws;
    float* amp_buf = (float*)(ws + 1228800);
    double* Xp = (double*)(ws + 1228800 + 2949120);

    dft_kernel<<<dim3(NBC, FMAX / 256, NCH), 256, 0, stream>>>(x, Xp);
    band_kernel<<<dim3(NBC, NBANDS, 2), 256, 0, stream>>>(Xp, idx_buf, amp_buf);
    mi_kernel<<<NBC * PHA_N, 256, 0, stream>>>(idx_buf, amp_buf, out);
}

// Round 5
// 148.555 us; speedup vs baseline: 1.1055x; 1.1055x over previous
//
#include <hip/hip_runtime.h>
#include <math.h>

#ifndef M_PI
#define M_PI 3.14159265358979323846
#endif

#define T 2048
#define EDGE 256
#define TT 1536            // trimmed timesteps
#define PHA_N 50
#define AMP_N 30
#define NBANDS 80
#define NBINS 18
#define NBC 16             // B*C = 2*8
#define FMAX 768           // forward DFT bins stored [0, FMAX); max needed bin = 634
#define NCH 16             // t-chunks for forward DFT
#define CHLEN (T / NCH)    // 128
#define QS 4               // t-quarters for mi_part
#define QT (TT / QS)       // 384

// Inclusive frequency-bin range [fl, fh] for a band, replicating the
// reference's float32 band edges vs exact quarter-Hz freq grid.
__device__ __forceinline__ void band_range(int band, int* fl, int* fh) {
    double lo, hi;
    if (band < PHA_N) {
        double mid = 2.0 + (double)band * (18.0 / 49.0);   // linspace(2,20,50)
        lo = (double)(float)(mid * 0.75);
        hi = (double)(float)(mid * 1.25);
    } else {
        int j = band - PHA_N;
        double mid = 60.0 + (double)j * (81.0 / 29.0);     // linspace(60,141,30)
        lo = (double)(float)(mid * 0.875);
        hi = (double)(float)(mid * 1.125);
    }
    int l = (int)ceil(lo * 4.0);     // freq = 0.25*f ; f >= 4*lo
    int h = (int)floor(hi * 4.0);    // f <= 4*hi
    if (l < 1) l = 1;
    if (h > FMAX - 1) h = FMAX - 1;
    *fl = l; *fh = h;
}

// Kernel A: chunked forward DFT partials via complex oscillator recurrence.
__global__ void dft_kernel(const float* __restrict__ x, double* __restrict__ Xp) {
    __shared__ float xs[CHLEN + 8];        // pad 8 floats (2 float4) of zeros
    const int bc = blockIdx.x;
    const int fb = blockIdx.y;
    const int ch = blockIdx.z;
    const int tid = threadIdx.x;
    const int t0 = ch * CHLEN;
    if (tid < CHLEN) xs[tid] = x[bc * T + t0 + tid];
    if (tid < 8) xs[CHLEN + tid] = 0.0f;
    __syncthreads();
    const int f = fb * 256 + tid;
    const double om = 2.0 * M_PI / (double)T;
    double s0, c0, sw, cw;
    sincos(om * (double)((f * t0) & (T - 1)), &s0, &c0);
    sincos(om * (double)(f & (T - 1)), &sw, &cw);
    double curR = c0, curI = -s0;          // e^{-i th0}
    const double wR = cw, wI = -sw;        // e^{-i om f}
    double accR = 0.0, accI = 0.0;
    const float4* xs4 = (const float4*)xs;
    float4 a0 = xs4[0], a1 = xs4[1];
    for (int q = 0; q < CHLEN / 4; ++q) {
        float4 a2 = xs4[q + 2];            // prefetch, used 2 iters later
        #pragma unroll
        for (int u = 0; u < 4; ++u) {
            double v = (double)((u == 0) ? a0.x : (u == 1) ? a0.y : (u == 2) ? a0.z : a0.w);
            accR += v * curR;
            accI += v * curI;
            double nR = curR * wR - curI * wI;
            double nI = curR * wI + curI * wR;
            curR = nR; curI = nI;
        }
        a0 = a1; a1 = a2;
    }
    Xp[(size_t)((bc * FMAX + f) * NCH + ch) * 2 + 0] = accR;
    Xp[(size_t)((bc * FMAX + f) * NCH + ch) * 2 + 1] = accI;
}

// Kernel A2: reduce NCH chunk partials -> Xf[bc][f] (complex double)
__global__ void reduce_kernel(const double* __restrict__ Xp, double* __restrict__ Xf) {
    const int gid = blockIdx.x * 256 + threadIdx.x;   // 0..12287 = bc*FMAX+f
    const double* p = Xp + (size_t)gid * NCH * 2;
    double r = 0.0, im = 0.0;
    #pragma unroll
    for (int c = 0; c < NCH; ++c) { r += p[2 * c]; im += p[2 * c + 1]; }
    Xf[2 * gid + 0] = r;
    Xf[2 * gid + 1] = im;
}

// Kernel B: per (bc, band, t-half) analytic-signal synthesis via oscillator
// recurrence over band bins. Phase bands fp64 (bin decision); amp bands fp32.
// Bands launched largest-first (band = 79 - y) to smooth the imbalance tail.
#define NJ 3
__global__ void band_kernel(const double* __restrict__ Xf,
                            unsigned char* __restrict__ idx_buf,
                            float* __restrict__ amp_buf) {
    __shared__ double sXr[164];
    __shared__ double sXi[164];
    const int bc = blockIdx.x;
    const int band = (NBANDS - 1) - blockIdx.y;   // biggest bands first
    const int half = blockIdx.z;
    const int tid = threadIdx.x;
    int fl, fh;
    band_range(band, &fl, &fh);
    const int nb = fh - fl + 1;
    const double om = 2.0 * M_PI / (double)T;

    if (band < PHA_N) {
        // ---------- fp64 phase path ----------
        for (int i = tid; i < nb; i += 256) {
            sXr[i] = Xf[(size_t)(bc * FMAX + fl + i) * 2 + 0];
            sXi[i] = Xf[(size_t)(bc * FMAX + fl + i) * 2 + 1];
        }
        __syncthreads();
        double curR[NJ], curI[NJ], wR[NJ], wI[NJ], accR[NJ], accI[NJ];
        #pragma unroll
        for (int j = 0; j < NJ; ++j) {
            const int t = tid + j * 256 + half * 768 + EDGE;
            double s, c;
            sincos(om * (double)((fl * t) & (T - 1)), &s, &c);
            curR[j] = c; curI[j] = s;          // e^{+i om fl t}
            sincos(om * (double)(t & (T - 1)), &s, &c);
            wR[j] = c; wI[j] = s;              // e^{+i om t}
            accR[j] = 0.0; accI[j] = 0.0;
        }
        #pragma unroll 2
        for (int i = 0; i < nb; ++i) {
            const double Xr = sXr[i], Xi = sXi[i];   // broadcast read
            #pragma unroll
            for (int j = 0; j < NJ; ++j) {
                accR[j] += Xr * curR[j] - Xi * curI[j];
                accI[j] += Xr * curI[j] + Xi * curR[j];
                double nR = curR[j] * wR[j] - curI[j] * wI[j];
                double nI = curR[j] * wI[j] + curI[j] * wR[j];
                curR[j] = nR; curI[j] = nI;
            }
        }
        const double width = 2.0 * M_PI / (double)NBINS;
        #pragma unroll
        for (int j = 0; j < NJ; ++j) {
            const int trel = tid + j * 256 + half * 768;
            double pha = atan2(accI[j], accR[j]);        // (-pi, pi]
            int b = (int)floor((pha + M_PI) / width);
            if (b < 0) b = 0;
            if (b > NBINS - 1) b = NBINS - 1;
            idx_buf[(size_t)(bc * PHA_N + band) * TT + trel] = (unsigned char)b;
        }
    } else {
        // ---------- fp32 amplitude path ----------
        float* fXr = (float*)sXr;
        float* fXi = (float*)sXi;
        for (int i = tid; i < nb; i += 256) {
            fXr[i] = (float)Xf[(size_t)(bc * FMAX + fl + i) * 2 + 0];
            fXi[i] = (float)Xf[(size_t)(bc * FMAX + fl + i) * 2 + 1];
        }
        __syncthreads();
        float curR[NJ], curI[NJ], wRf[NJ], wIf[NJ], accR[NJ], accI[NJ];
        #pragma unroll
        for (int j = 0; j < NJ; ++j) {
            const int t = tid + j * 256 + half * 768 + EDGE;
            double s, c;
            sincos(om * (double)((fl * t) & (T - 1)), &s, &c);
            curR[j] = (float)c; curI[j] = (float)s;
            sincos(om * (double)(t & (T - 1)), &s, &c);
            wRf[j] = (float)c; wIf[j] = (float)s;
            accR[j] = 0.0f; accI[j] = 0.0f;
        }
        #pragma unroll 2
        for (int i = 0; i < nb; ++i) {
            const float Xr = fXr[i], Xi = fXi[i];
            #pragma unroll
            for (int j = 0; j < NJ; ++j) {
                accR[j] += Xr * curR[j] - Xi * curI[j];
                accI[j] += Xr * curI[j] + Xi * curR[j];
                float nR = curR[j] * wRf[j] - curI[j] * wIf[j];
                float nI = curR[j] * wIf[j] + curI[j] * wRf[j];
                curR[j] = nR; curI[j] = nI;
            }
        }
        #pragma unroll
        for (int j = 0; j < NJ; ++j) {
            const int trel = tid + j * 256 + half * 768;
            float amp = sqrtf(accR[j] * accR[j] + accI[j] * accI[j]) * (2.0f / (float)T);
            amp_buf[(size_t)(bc * AMP_N + (band - PHA_N)) * TT + trel] = amp;
        }
    }
}

// Kernel C1: per (bc, phase band p, t-quarter): fused counts + bin sums,
// fp32 LDS partials, atomicAdd to global Sums[pair][31][18].
#define PK 19   // padded bin stride for partials
#define NROW 31 // 30 amp bands + counts row
__global__ void mi_part(const unsigned char* __restrict__ idx_buf,
                        const float* __restrict__ amp_buf,
                        float* __restrict__ Sums) {
    __shared__ float part[NROW * 8 * PK];     // row = tid = a*8+g
    const int blk = blockIdx.x;               // bc*50 + p
    const int q = blockIdx.y;                 // t-quarter
    const int bc = blk / PHA_N;
    const int p = blk % PHA_N;
    const int tid = threadIdx.x;

    for (int i = tid; i < NROW * 8 * PK; i += 256) part[i] = 0.0f;
    __syncthreads();

    if (tid < NROW * 8) {
        const int a = tid >> 3;     // 0..30 (30 == counts row)
        const int g = tid & 7;      // contiguous 48-t chunk per thread
        const unsigned int* sp =
            (const unsigned int*)(idx_buf + (size_t)(bc * PHA_N + p) * TT + q * QT) + g * 12;
        const float4* ap = (a < AMP_N)
            ? (const float4*)(amp_buf + (size_t)(bc * AMP_N + a) * TT + q * QT) + g * 12
            : (const float4*)0;
        float* myp = part + tid * PK;
        for (int it = 0; it < 12; ++it) {
            const unsigned int pk = sp[it];
            float4 v;
            if (a < AMP_N) v = ap[it];
            else { v.x = 1.0f; v.y = 1.0f; v.z = 1.0f; v.w = 1.0f; }
            myp[pk & 0xff]         += v.x;
            myp[(pk >> 8) & 0xff]  += v.y;
            myp[(pk >> 16) & 0xff] += v.z;
            myp[(pk >> 24) & 0xff] += v.w;
        }
    }
    __syncthreads();

    for (int i = tid; i < NROW * NBINS; i += 256) {
        const int row = i / NBINS, k = i - row * NBINS;
        float s = 0.0f;
        #pragma unroll
        for (int g = 0; g < 8; ++g) s += part[(row * 8 + g) * PK + k];
        atomicAdd(&Sums[((size_t)blk * NROW + row) * NBINS + k], s);
    }
}

// Kernel C2: MI from Sums. One thread per (pair, amp band).
__global__ void mi_final(const float* __restrict__ Sums, float* __restrict__ out) {
    const int gid = blockIdx.x * 256 + threadIdx.x;
    if (gid >= NBC * PHA_N * AMP_N) return;
    const int pair = gid / AMP_N;
    const int a = gid - pair * AMP_N;
    const float* srow = Sums + ((size_t)pair * NROW + a) * NBINS;
    const float* crow = Sums + ((size_t)pair * NROW + AMP_N) * NBINS;   // counts
    double m[NBINS], tot = 0.0;
    #pragma unroll
    for (int k = 0; k < NBINS; ++k) {
        double cnt = (double)crow[k];
        double denom = cnt > 1e-9 ? cnt : 1e-9;
        m[k] = (double)srow[k] / denom;
        tot += m[k];
    }
    double dt = tot > 1e-9 ? tot : 1e-9;
    double acc = 0.0;
    #pragma unroll
    for (int k = 0; k < NBINS; ++k) {
        double pr = m[k] / dt;
        acc += pr * log(pr + 1e-9);
    }
    const double lognb = log((double)NBINS);
    out[gid] = (float)((lognb + acc) / lognb);
}

extern "C" void kernel_launch(void* const* d_in, const int* in_sizes, int n_in,
                              void* d_out, int out_size, void* d_ws, size_t ws_size,
                              hipStream_t stream) {
    const float* x = (const float*)d_in[0];
    float* out = (float*)d_out;
    char* ws = (char*)d_ws;
    // workspace layout (~9.3 MB; all regions written before read each call):
    //   idx_buf: 16*50*1536 u8                       = 1,228,800 B @ 0
    //   amp_buf: 16*30*1536 f32                      = 2,949,120 B @ 1,228,800
    //   Xp:      16*768*16 chunks complex double     = 3,145,728 B @ 4,177,920
    //   Xf:      16*768 complex double               =   196,608 B @ 7,323,648
    //   Sums:    800*31*18 f32                       = 1,785,600 B @ 7,520,256
    unsigned char* idx_buf = (unsigned char*)ws;
    float* amp_buf = (float*)(ws + 1228800);
    double* Xp = (double*)(ws + 4177920);
    double* Xf = (double*)(ws + 7323648);
    float* Sums = (float*)(ws + 7520256);

    hipMemsetAsync(Sums, 0, (size_t)NBC * PHA_N * NROW * NBINS * 4, stream);
    dft_kernel<<<dim3(NBC, FMAX / 256, NCH), 256, 0, stream>>>(x, Xp);
    reduce_kernel<<<NBC * FMAX / 256, 256, 0, stream>>>(Xp, Xf);
    band_kernel<<<dim3(NBC, NBANDS, 2), 256, 0, stream>>>(Xf, idx_buf, amp_buf);
    mi_part<<<dim3(NBC * PHA_N, QS), 256, 0, stream>>>(idx_buf, amp_buf, Sums);
    mi_final<<<(NBC * PHA_N * AMP_N + 255) / 256, 256, 0, stream>>>(Sums, out);
}